// Round 11
// baseline (492.341 us; speedup 1.0000x reference)
//
#include <hip/hip_runtime.h>
#include <hip/hip_bf16.h>

// MultiHeadAttention: N=2048, H=16, D=128. f32 in, f32 out, int32 mask.
// R10->R11: BISECT. R10 (panels + j-split) failed 0.2675 despite 3 clean
// audits of the panel permutations. Revert panels (T1) -> R8-verbatim proj
// and attn inner loop (row-major qp / vpT global B-frag loads, both
// HW-validated by R8's pass). Keep only j-split x2 (T2): block = 4 waves =
// 2 i-tiles x 2 j-halves, grid (16,64) -> 4096 waves = 16/CU (2x R8
// occupancy), end-of-kernel LDS combine (2 barriers, outside hot loop).
// PASS => combine exonerated, panels indicted (re-land alone next).
// FAIL => combine indicted.

#define HN 16
#define NN 2048
#define DD 128
#define PB_PITCH 72

typedef __attribute__((ext_vector_type(8))) short short8;   // MFMA A/B frag
typedef __attribute__((ext_vector_type(4))) short short4v;
typedef __attribute__((ext_vector_type(4))) float float4v;  // MFMA C/D frag

__device__ inline unsigned short f2bf(float f) {
    unsigned int u = __builtin_bit_cast(unsigned int, f);
    unsigned int r = (u + 0x7fffu + ((u >> 16) & 1u)) >> 16;  // RNE
    return (unsigned short)r;
}

__device__ inline short8 ld_bf8(const float* __restrict__ p) {
    const float4v a = *(const float4v*)p;
    const float4v b = *(const float4v*)(p + 4);
    short8 r;
    r[0] = (short)f2bf(a[0]); r[1] = (short)f2bf(a[1]);
    r[2] = (short)f2bf(a[2]); r[3] = (short)f2bf(a[3]);
    r[4] = (short)f2bf(b[0]); r[5] = (short)f2bf(b[1]);
    r[6] = (short)f2bf(b[2]); r[7] = (short)f2bf(b[3]);
    return r;
}

__device__ inline short8 ld2x4(const unsigned short* p) {
    const short4v lo = *(const short4v*)p;
    const short4v hi = *(const short4v*)(p + 4);
    short8 r;
    r[0] = lo[0]; r[1] = lo[1]; r[2] = lo[2]; r[3] = lo[3];
    r[4] = hi[0]; r[5] = hi[1]; r[6] = hi[2]; r[7] = hi[3];
    return r;
}

__global__ void sentinel_kernel(float* out, int n) {
    int i = blockIdx.x * 256 + threadIdx.x;
    if (i < n) out[i] = 2.0f;
}

// ---------------------------------------------------------------------------
// Kernel A: projections (R8 verbatim). grid = (32 row-tiles, 16 heads, 3).
// t<2: qp/kp row-major [n][d].  t==2: vpT [d][n] via operand swap.
// ---------------------------------------------------------------------------
__global__ __launch_bounds__(256) void proj_kernel(
    const float* __restrict__ q,
    const float* __restrict__ k,
    const float* __restrict__ v,
    const float* __restrict__ Qw,
    const float* __restrict__ Kw,
    const float* __restrict__ Vw,
    unsigned short* __restrict__ ws)
{
    __shared__ __align__(16) unsigned short Wt[128 * 132];  // Wt[e][d] = bf16(W[d][e])
    const int t = blockIdx.z, h = blockIdx.y, rb = blockIdx.x;
    const int tid = threadIdx.x;
    const float* in = (t == 0) ? q : ((t == 1) ? k : v);
    const float* W  = ((t == 0) ? Qw : ((t == 1) ? Kw : Vw)) + h * DD * DD;
    unsigned short* out = ws + (size_t)t * (HN * NN * DD) + (size_t)h * (NN * DD);

    for (int idx2 = tid * 2; idx2 < DD * DD; idx2 += 512) {
        const int d = idx2 >> 7, e = idx2 & 127;
        const float2 w2 = *(const float2*)(W + idx2);
        Wt[(e + 0) * 132 + d] = f2bf(w2.x);
        Wt[(e + 1) * 132 + d] = f2bf(w2.y);
    }
    __syncthreads();

    const int wave = tid >> 6, lane = tid & 63;
    const int quad = lane >> 4, l16 = lane & 15;
    const int row0 = rb * 64 + wave * 16;

    float4v acc[8];
    for (int c = 0; c < 8; c++) acc[c] = {0.f, 0.f, 0.f, 0.f};

    if (t < 2) {
        for (int kk = 0; kk < 4; kk++) {
            const short8 a = ld_bf8(in + (size_t)(row0 + l16) * DD + kk * 32 + quad * 8);
            for (int c = 0; c < 8; c++) {
                const short8 b = ld2x4(&Wt[(c * 16 + l16) * 132 + kk * 32 + quad * 8]);
                acc[c] = __builtin_amdgcn_mfma_f32_16x16x32_bf16(a, b, acc[c], 0, 0, 0);
            }
        }
        for (int c = 0; c < 8; c++)
            for (int r = 0; r < 4; r++)
                out[(size_t)(row0 + quad * 4 + r) * DD + c * 16 + l16] = f2bf(acc[c][r]);
    } else {
        for (int kk = 0; kk < 4; kk++) {
            const short8 bv = ld_bf8(in + (size_t)(row0 + l16) * DD + kk * 32 + quad * 8);
            for (int c = 0; c < 8; c++) {
                const short8 aw = ld2x4(&Wt[(c * 16 + l16) * 132 + kk * 32 + quad * 8]);
                acc[c] = __builtin_amdgcn_mfma_f32_16x16x32_bf16(aw, bv, acc[c], 0, 0, 0);
            }
        }
        for (int c = 0; c < 8; c++)
            for (int r = 0; r < 4; r++)
                out[(size_t)(c * 16 + quad * 4 + r) * NN + row0 + l16] = f2bf(acc[c][r]);
    }
}

// ---------------------------------------------------------------------------
// Kernel B: attn = R8 inner loop + j-split x2. grid = (16 heads, 64 i-grps).
// wave w: itile = by*2 + (w&1), j-half = (w>>1). Combine at kernel end.
// ---------------------------------------------------------------------------
__global__ __launch_bounds__(256) void attn_kernel(
    unsigned short* __restrict__ ws,
    const int* __restrict__ mask)
{
    __shared__ __align__(16) unsigned char smem[16512];
    unsigned short* Pb = (unsigned short*)smem;    // 4 x 16 x 72 shorts = 9216 B
    float* combO = (float*)smem;                   // 2 x 2048 f32 = 16384 B
    float* combL = (float*)(smem + 16384);         // 32 f32

    const int h = blockIdx.x, by = blockIdx.y;     // head-major for XCD locality
    const int tid = threadIdx.x;
    const int wave = tid >> 6, lane = tid & 63;
    const int quad = lane >> 4, l16 = lane & 15;

    const unsigned short* qp  = ws + (size_t)h * (NN * DD);
    const unsigned short* kp  = ws + (size_t)(HN * NN * DD) + (size_t)h * (NN * DD);
    const unsigned short* vpT = ws + (size_t)(2 * HN * NN * DD) + (size_t)h * (NN * DD);
    unsigned short* ao = ws + (size_t)(3 * HN * NN * DD);  // [N][H*D]

    const int itile = by * 2 + (wave & 1);
    const int jbase = (wave >> 1) * (NN / 2);
    const int gi_base = itile * 16 + quad * 4;

    const float c1 = 0.022097086912079612f * 1.44269504088896f;  // scale*log2e
    const float c2 = -5.0f * 1.44269504088896f;

    short8 ones;
    for (int i = 0; i < 8; i++) ones[i] = (short)0x3F80;  // bf16 1.0

    // kp A-frags (16 i-rows, reused all j-iters)
    short8 afragK[4];
    {
        const int row = itile * 16 + l16;
        for (int kk = 0; kk < 4; kk++)
            afragK[kk] = *(const short8*)(kp + (size_t)row * DD + kk * 32 + quad * 8);
    }

    unsigned short* PbW = &Pb[wave * 16 * PB_PITCH];

    float4v o[8];
    for (int c = 0; c < 8; c++) o[c] = {0.f, 0.f, 0.f, 0.f};
    float4v lacc = {0.f, 0.f, 0.f, 0.f};

    for (int jt = 0; jt < 16; jt++) {
        const int j0 = jbase + jt * 64;

        // S = kp · qp^T (16x64): R8-verbatim global B-frag loads
        float4v s[4];
        for (int c = 0; c < 4; c++) s[c] = {0.f, 0.f, 0.f, 0.f};
#pragma unroll
        for (int kk = 0; kk < 4; kk++) {
#pragma unroll
            for (int c = 0; c < 4; c++) {
                const short8 b = *(const short8*)(qp + (size_t)(j0 + c * 16 + l16) * DD + kk * 32 + quad * 8);
                s[c] = __builtin_amdgcn_mfma_f32_16x16x32_bf16(afragK[kk], b, s[c], 0, 0, 0);
            }
        }

        // static-max softmax -> Pb (per-wave LDS, lgkmcnt-ordered)
#pragma unroll
        for (int r = 0; r < 4; r++) {
            const size_t mrow = (size_t)(gi_base + r) * NN + j0;
#pragma unroll
            for (int c = 0; c < 4; c++) {
                const int mv = mask[mrow + c * 16 + l16];
                const float x = mv ? fmaf(s[c][r], c1, c2) : -72.0f;
                PbW[(quad * 4 + r) * PB_PITCH + c * 16 + l16] = f2bf(__builtin_amdgcn_exp2f(x));
            }
        }

        // O += P·V ; l += P·1 : R8-verbatim vpT B-frag loads
#pragma unroll
        for (int ks = 0; ks < 2; ks++) {
            const short8 ap = *(const short8*)(&PbW[l16 * PB_PITCH + ks * 32 + quad * 8]);
#pragma unroll
            for (int dc = 0; dc < 8; dc++) {
                const short8 bv = *(const short8*)(vpT + (size_t)(dc * 16 + l16) * NN + j0 + ks * 32 + quad * 8);
                o[dc] = __builtin_amdgcn_mfma_f32_16x16x32_bf16(ap, bv, o[dc], 0, 0, 0);
            }
            lacc = __builtin_amdgcn_mfma_f32_16x16x32_bf16(ap, ones, lacc, 0, 0, 0);
        }
    }

    // cross-j-half combine: wave w (half 0) pairs with w+2 (half 1), same itile
    __syncthreads();
    if (wave >= 2) {
        float* Ob = combO + (wave - 2) * 2048;
        for (int dc = 0; dc < 8; dc++)
            for (int r = 0; r < 4; r++)
                Ob[(quad * 4 + r) * 128 + dc * 16 + l16] = o[dc][r];
        if (l16 == 0)
            for (int r = 0; r < 4; r++)
                combL[(wave - 2) * 16 + quad * 4 + r] = lacc[r];
    }
    __syncthreads();
    if (wave < 2) {
        const float* Ob = combO + wave * 2048;
        for (int dc = 0; dc < 8; dc++)
            for (int r = 0; r < 4; r++)
                o[dc][r] += Ob[(quad * 4 + r) * 128 + dc * 16 + l16];
        for (int r = 0; r < 4; r++) {
            const float l = lacc[r] + combL[wave * 16 + quad * 4 + r];
            const float inv = (l > 0.f) ? (1.0f / l) : 0.f;
            const int gi = gi_base + r;
            for (int dc = 0; dc < 8; dc++)
                ao[(size_t)gi * (HN * DD) + h * DD + dc * 16 + l16] = f2bf(o[dc][r] * inv);
        }
    }
}

// ---------------------------------------------------------------------------
// Kernel C: final GEMM (R8 verbatim). grid = (32 i, 4 e-cols).
// ---------------------------------------------------------------------------
__global__ __launch_bounds__(256) void final_kernel(
    const unsigned short* __restrict__ ao,
    const float* __restrict__ last,
    float* __restrict__ outp)
{
    __shared__ __align__(16) unsigned short lt[32 * 68];  // [e_local][k_local]
    const int tid = threadIdx.x;
    const int wave = tid >> 6, lane = tid & 63;
    const int quad = lane >> 4, l16 = lane & 15;
    const int i0 = blockIdx.x * 64;
    const int e0 = blockIdx.y * 32;

    float4v acc[2];
    acc[0] = {0.f, 0.f, 0.f, 0.f};
    acc[1] = {0.f, 0.f, 0.f, 0.f};

    for (int k0 = 0; k0 < HN * DD; k0 += 64) {
        for (int idx2 = tid * 2; idx2 < 64 * 32; idx2 += 512) {
            const int kk = idx2 >> 5, e = idx2 & 31;
            const float2 w2 = *(const float2*)(last + (size_t)(k0 + kk) * DD + e0 + e);
            lt[(e + 0) * 68 + kk] = f2bf(w2.x);
            lt[(e + 1) * 68 + kk] = f2bf(w2.y);
        }
        __syncthreads();
        for (int ks = 0; ks < 2; ks++) {
            const short8 a = *(const short8*)(ao + (size_t)(i0 + wave * 16 + l16) * (HN * DD) + k0 + ks * 32 + quad * 8);
            for (int dc = 0; dc < 2; dc++) {
                const short8 b = ld2x4(&lt[(dc * 16 + l16) * 68 + ks * 32 + quad * 8]);
                acc[dc] = __builtin_amdgcn_mfma_f32_16x16x32_bf16(a, b, acc[dc], 0, 0, 0);
            }
        }
        __syncthreads();
    }
    for (int r = 0; r < 4; r++)
        for (int dc = 0; dc < 2; dc++)
            outp[(size_t)(i0 + wave * 16 + quad * 4 + r) * DD + e0 + dc * 16 + l16] = acc[dc][r];
}

extern "C" void kernel_launch(void* const* d_in, const int* in_sizes, int n_in,
                              void* d_out, int out_size, void* d_ws, size_t ws_size,
                              hipStream_t stream)
{
    const float* q    = (const float*)d_in[0];
    const float* k    = (const float*)d_in[1];
    const float* v    = (const float*)d_in[2];
    const int*   mask = (const int*)d_in[3];
    const float* Qw   = (const float*)d_in[4];
    const float* Kw   = (const float*)d_in[5];
    const float* Vw   = (const float*)d_in[6];
    const float* last = (const float*)d_in[7];
    unsigned short* ws  = (unsigned short*)d_ws;
    float* out = (float*)d_out;

    // ws (bf16): qp row-major | kp row-major | vpT [d][n] | ao [2048][2048]
    const size_t needed = (size_t)(3 * HN * NN * DD + NN * HN * DD) * sizeof(unsigned short);
    if (ws_size < needed) {
        sentinel_kernel<<<(out_size + 255) / 256, 256, 0, stream>>>(out, out_size);
        return;
    }

    proj_kernel<<<dim3(32, 16, 3), 256, 0, stream>>>(q, k, v, Qw, Kw, Vw, ws);
    attn_kernel<<<dim3(16, 64), 256, 0, stream>>>(ws, mask);
    final_kernel<<<dim3(32, 4), 256, 0, stream>>>(ws + (size_t)3 * HN * NN * DD, last, out);
}